// Round 4
// baseline (125.837 us; speedup 1.0000x reference)
//
#include <hip/hip_runtime.h>
#include <stdint.h>

#define BATCH 16
#define CIN   128
#define COUT  128
#define IMG_H 64
#define IMG_W 64
#define HW    4096
#define KTOT  1152          // 9*128
#define XH    66
#define XW    66
#define NCQ   16            // ci groups of 8
#define NSTEPS 18           // K-steps of 64 in wt4 layout
#define ASTEP 8192          // A elems per step-tile: 8cq*128co*8e  (16 KB)
#define AHALF 4096          // A elems per half-tile: 4cq*128co*8e  ( 8 KB)
#define NHSTEP 36           // 1152 / 32

typedef __attribute__((ext_vector_type(8))) __bf16 bf16x8;
typedef __attribute__((ext_vector_type(4))) float  f32x4;
typedef __attribute__((address_space(1))) const void* gas_p;
typedef __attribute__((address_space(3))) void*       las_p;

static __device__ __forceinline__ unsigned short f2bf(float f) {
  union { float f; uint32_t u; } c; c.f = f;
  uint32_t r = c.u + 0x7fffu + ((c.u >> 16) & 1u);   // RNE
  return (unsigned short)(r >> 16);
}

static __device__ __forceinline__ void gload_lds16(const unsigned short* g, unsigned short* l) {
  __builtin_amdgcn_global_load_lds((gas_p)g, (las_p)l, 16, 0, 0);
}

// ---- fused prep (unchanged layouts) ----
// blocks [0, 1024): x fp32 NCHW -> bf16 xpad[b][66][16cq][66][8], zero halo
// blocks [1024, 1312): w fp32 [b][co][ci][3][3] -> wt4[b][step18][cq8][co128][e8]
__global__ void prep_fused(const float* __restrict__ x, const float* __restrict__ w,
                           unsigned short* __restrict__ wt4, unsigned short* __restrict__ xpad) {
  const int t = threadIdx.x;
  if (blockIdx.x < BATCH * IMG_H) {
    // ---------------- prep_x ----------------
    __shared__ uint32_t tile[64 * 68];              // [wcol][ci2], pad 68 words
    const int b = blockIdx.x >> 6;
    const int h = blockIdx.x & 63;
    const float* xb = x + (size_t)b * CIN * HW + h * IMG_W;
    uint4* xp4 = (uint4*)xpad;                      // 16B chunks

    const int lane16 = t & 15;
    const int g      = t >> 4;
#pragma unroll
    for (int it = 0; it < 4; ++it) {
      const int ci = it * 32 + g * 2;
      const float4 va = *(const float4*)(xb + (size_t)ci * HW + lane16 * 4);
      const float4 vb = *(const float4*)(xb + (size_t)(ci + 1) * HW + lane16 * 4);
      const float av[4] = {va.x, va.y, va.z, va.w};
      const float bv[4] = {vb.x, vb.y, vb.z, vb.w};
#pragma unroll
      for (int cc = 0; cc < 4; ++cc)
        tile[(lane16 * 4 + cc) * 68 + it * 16 + g] =
            (uint32_t)f2bf(av[cc]) | ((uint32_t)f2bf(bv[cc]) << 16);
    }
    __syncthreads();

    const uint32_t rbase = ((uint32_t)b * XH + h + 1) * NCQ;
#pragma unroll
    for (int it = 0; it < 4; ++it) {
      const int o   = it * 256 + t;
      const int cqg = o >> 6;
      const int wc  = o & 63;
      const uint4 v = *(const uint4*)&tile[wc * 68 + cqg * 4];
      xp4[(rbase + cqg) * XW + wc + 1] = v;
    }
    if (t < 32) {
      const int cqg = t & 15;
      const int col = (t >> 4) ? 65 : 0;
      xp4[(rbase + cqg) * XW + col] = make_uint4(0, 0, 0, 0);
    }
    if (h == 0) {
      const uint32_t r0  = (uint32_t)b * XH * NCQ * XW;
      const uint32_t r65 = ((uint32_t)b * XH + 65) * NCQ * XW;
      for (int i = t; i < NCQ * XW; i += 256) {
        xp4[r0 + i]  = make_uint4(0, 0, 0, 0);
        xp4[r65 + i] = make_uint4(0, 0, 0, 0);
      }
    }
  } else {
    // ---------------- prep_w ----------------
    const int idx  = blockIdx.x - BATCH * IMG_H;
    const int b    = idx / NSTEPS;
    const int step = idx % NSTEPS;
    const int khkw = step >> 1;
    const int cib  = (step & 1) << 6;
    const float* wb = w + (size_t)b * COUT * KTOT;
    unsigned short* dst = wt4 + ((size_t)b * NSTEPS + step) * ASTEP;
#pragma unroll
    for (int i = 0; i < 4; ++i) {
      const int c  = i * 256 + t;                 // chunk 0..1023
      const int cq = c >> 7;
      const int co = c & 127;
      const int ci0 = cib + cq * 8;
      const float* src = wb + (size_t)co * KTOT + (size_t)ci0 * 9 + khkw;
      uint32_t p[4];
#pragma unroll
      for (int e = 0; e < 4; ++e)
        p[e] = (uint32_t)f2bf(src[(2 * e) * 9]) | ((uint32_t)f2bf(src[(2 * e + 1) * 9]) << 16);
      *(uint4*)&dst[(size_t)c * 8] = make_uint4(p[0], p[1], p[2], p[3]);
    }
  }
}

// ---- main implicit-GEMM: 128co x 256px (4 output rows) per block ----
// Persistent-B: all 6 needed xpad rows (16 cq, 66 px) staged ONCE (101 KB);
// K-loop streams only A in 36 half-steps (8 KB, double-buffered). The 3x3
// kernel's kw shift is a read offset into persistent B, not a re-stage.
// 8 waves of 64co x 64px (4x4 fragments). 256 blocks = exactly 1/CU.
__global__ __launch_bounds__(512, 2) void dynconv_gemm(
    const unsigned short* __restrict__ wt4,   // [B][18][8][128][8] bf16
    const unsigned short* __restrict__ xpad,  // [B][66][16][66][8] bf16, halo=0
    float* __restrict__ out) {                // [B][COUT][64][64] fp32
  __shared__ alignas(16) unsigned short Ah[2][AHALF];       // 2 x 8 KB
  __shared__ alignas(16) unsigned short Bp[6][NCQ][XW * 8]; // 101.4 KB

  const int t   = threadIdx.x;
  const int bid = blockIdx.x;
  // XCD-pinned batches: 2 batches per XCD (wt4+xpad slabs ~2.8 MB < 4 MB L2)
  const int xcd = bid & 7;
  const int idx = bid >> 3;                 // 0..31 within XCD
  const int b   = xcd * 2 + (idx >> 4);     // batch
  const int oh0 = (idx & 15) * 4;           // first of 4 output rows

  const int lane = t & 63;
  const int wave = t >> 6;                  // 0..7
  const int wm   = (wave & 1) << 6;         // co offset of wave (0/64)
  const int prow = wave >> 1;               // output-row of wave (0..3)
  const int l15  = lane & 15;
  const int quad = lane >> 4;

  // A source: thread's chunk = t within each 8 KB half-tile
  const unsigned short* abase = wt4 + (size_t)b * NSTEPS * ASTEP + (size_t)t * 8;
  const unsigned short* xb = xpad + (size_t)b * XH * NCQ * XW * 8;

  f32x4 acc[4][4] = {};

  // ---- prologue: persistent B (6 rows x 16 cq x 66 chunks) + A half-tile 0 ----
  // 96 (row,cq) pairs, 12 per wave; each row = 66 chunks staged as two
  // overlapping 64-chunk gloads (chunks 0..63 and 2..65; overlap writes
  // identical bytes, benign). NOTE: global src is PER-LANE (+lane*8);
  // LDS dst is wave-uniform (HW adds lane*16B).
#pragma unroll
  for (int k = 0; k < 12; ++k) {
    const int p   = wave * 12 + k;
    const int row = p >> 4;
    const int cq  = p & 15;
    const unsigned short* src =
        xb + ((size_t)((oh0 + row) * NCQ + cq) * XW + (size_t)lane) * 8;
    unsigned short* dst = &Bp[row][cq][0];
    gload_lds16(src, dst);                 // chunks lane   -> slot lane
    gload_lds16(src + 16, dst + 16);       // chunks lane+2 -> slot lane+2
  }
  gload_lds16(abase, &Ah[0][wave * 512]);  // half-step 0 (step 0, cq 0..3)
  __syncthreads();

  // ---- K-loop: 36 half-steps of 32 ci each; stream A only ----
#pragma unroll 4
  for (int h = 0; h < NHSTEP; ++h) {
    const int u = h & 1;

    // prefetch next A half-tile; latency hides under the LDS reads + MFMAs
    if (h + 1 < NHSTEP) {
      const int h2   = h + 1;
      const int kk2  = h2 >> 2;            // khkw
      const int q42  = h2 & 3;             // quarter within khkw (4cq)
      const int stp  = kk2 * 2 + (q42 >> 1);
      const size_t aoff = (size_t)stp * ASTEP + (size_t)(q42 & 1) * AHALF;
      gload_lds16(abase + aoff, &Ah[u ^ 1][wave * 512]);
    }

    const int khkw = h >> 2;
    const int q4   = h & 3;
    const int kh   = (khkw * 11) >> 5;
    const int kw   = khkw - kh * 3;

    bf16x8 af[4], bfr[4];
#pragma unroll
    for (int i = 0; i < 4; ++i)
      af[i] = *(const bf16x8*)&Ah[u][(quad * 128 + wm + i * 16 + l15) * 8];
#pragma unroll
    for (int j = 0; j < 4; ++j)
      bfr[j] = *(const bf16x8*)&Bp[kh + prow][q4 * 4 + quad][(kw + j * 16 + l15) * 8];
#pragma unroll
    for (int i = 0; i < 4; ++i)
#pragma unroll
      for (int j = 0; j < 4; ++j)
        acc[i][j] = __builtin_amdgcn_mfma_f32_16x16x32_bf16(af[i], bfr[j], acc[i][j], 0, 0, 0);

    // one barrier per half-step: drains A prefetch (vmcnt) and protects Ah[u]
    __syncthreads();
  }

  // ---- epilogue ----
  // co = wm + i*16 + quad*4 + r; px-in-tile = prow*64 + j*16 + l15 (0..255,
  // 4 contiguous output rows starting at oh0)
  float* obase = out + (size_t)b * COUT * HW + (size_t)oh0 * IMG_W;
  const int pxb = prow * 64;
#pragma unroll
  for (int i = 0; i < 4; ++i) {
#pragma unroll
    for (int r = 0; r < 4; ++r) {
      const int co = wm + i * 16 + quad * 4 + r;
      float* orow = obase + (size_t)co * HW;
#pragma unroll
      for (int j = 0; j < 4; ++j)
        orow[pxb + j * 16 + l15] = acc[i][j][r];
    }
  }
}

// ---- safety net: direct fp32 conv ----
__global__ void dynconv_naive(const float* __restrict__ x, const float* __restrict__ w,
                              float* __restrict__ out) {
  const int o   = blockIdx.x * 256 + threadIdx.x;
  const int pix = o & (HW - 1);
  const int co  = (o >> 12) & (COUT - 1);
  const int b   = o >> 19;
  const int oh  = pix >> 6, ow = pix & 63;
  const float* xb = x + (size_t)b * CIN * HW;
  const float* wb = w + ((size_t)b * COUT + co) * CIN * 9;
  float s = 0.f;
  for (int ci = 0; ci < CIN; ++ci) {
    const float* xc = xb + ci * HW;
    const float* wc = wb + ci * 9;
#pragma unroll
    for (int kh = 0; kh < 3; ++kh) {
      const int ih = oh + kh - 1;
      if ((unsigned)ih >= IMG_H) continue;
#pragma unroll
      for (int kw = 0; kw < 3; ++kw) {
        const int iw = ow + kw - 1;
        if ((unsigned)iw >= IMG_W) continue;
        s += xc[ih * IMG_W + iw] * wc[kh * 3 + kw];
      }
    }
  }
  out[o] = s;
}

extern "C" void kernel_launch(void* const* d_in, const int* in_sizes, int n_in,
                              void* d_out, int out_size, void* d_ws, size_t ws_size,
                              hipStream_t stream) {
  const float* x = (const float*)d_in[0];
  const float* w = (const float*)d_in[1];
  float* out = (float*)d_out;

  const size_t wt_bytes = (size_t)BATCH * NSTEPS * ASTEP * sizeof(unsigned short);       //  4.72 MB
  const size_t xp_bytes = (size_t)BATCH * XH * NCQ * XW * 8 * sizeof(unsigned short);    // 17.84 MB

  if (ws_size >= wt_bytes + xp_bytes) {
    unsigned short* wt4  = (unsigned short*)d_ws;
    unsigned short* xpad = (unsigned short*)((char*)d_ws + wt_bytes);
    prep_fused<<<BATCH * IMG_H + BATCH * NSTEPS, 256, 0, stream>>>(x, w, wt4, xpad);
    dynconv_gemm<<<256, 512, 0, stream>>>(wt4, xpad, out);
  } else {
    dynconv_naive<<<(BATCH * COUT * HW) / 256, 256, 0, stream>>>(x, w, out);
  }
}